// Round 2
// baseline (4656.798 us; speedup 1.0000x reference)
//
#include <hip/hip_runtime.h>
#include <hip/hip_bf16.h>

#define SEQ 2048
#define DM  1024
#define NH  16
#define HDM 64

typedef __hip_bfloat16 bf16;

__device__ __forceinline__ float toF(float x) { return x; }
__device__ __forceinline__ float toF(bf16 x)  { return __bfloat162float(x); }
__device__ __forceinline__ void  stF(float* p, float v) { *p = v; }
__device__ __forceinline__ void  stF(bf16* p, float v)  { *p = __float2bfloat16(v); }

// C[2048,1024] = A[2048,1024] @ B[1024,1024] + bias
// mode 0: C row-major [S, D]
// mode 1: C head-major [H][S][64]: C[((col>>6)*SEQ + row)*64 + (col&63)]
template <typename TA, typename TC>
__global__ __launch_bounds__(256) void gemm_bias(
    const TA* __restrict__ A, const float* __restrict__ B,
    const float* __restrict__ bias, TC* __restrict__ C, int mode)
{
  __shared__ __align__(16) float As[16][68];  // [k][m]
  __shared__ __align__(16) float Bs[16][68];  // [k][n]
  const int bm = blockIdx.y * 64;
  const int bn = blockIdx.x * 64;
  const int tid = threadIdx.x;
  const int tm = (tid >> 4) << 2;
  const int tn = (tid & 15) << 2;
  float acc[4][4] = {};
  for (int k0 = 0; k0 < DM; k0 += 16) {
#pragma unroll
    for (int r = 0; r < 4; ++r) {
      int idx = tid + r * 256;            // 0..1023
      int m = idx >> 4, k = idx & 15;     // A tile 64m x 16k
      As[k][m] = toF(A[(size_t)(bm + m) * DM + (k0 + k)]);
      int kk = idx >> 6, n = idx & 63;    // B tile 16k x 64n
      Bs[kk][n] = B[(size_t)(k0 + kk) * DM + (bn + n)];
    }
    __syncthreads();
#pragma unroll
    for (int k = 0; k < 16; ++k) {
      float4 a4 = *(const float4*)&As[k][tm];
      float4 b4 = *(const float4*)&Bs[k][tn];
      float av[4] = {a4.x, a4.y, a4.z, a4.w};
      float bv[4] = {b4.x, b4.y, b4.z, b4.w};
#pragma unroll
      for (int i2 = 0; i2 < 4; ++i2)
#pragma unroll
        for (int j2 = 0; j2 < 4; ++j2)
          acc[i2][j2] += av[i2] * bv[j2];
    }
    __syncthreads();
  }
#pragma unroll
  for (int i2 = 0; i2 < 4; ++i2) {
    int row = bm + tm + i2;
#pragma unroll
    for (int j2 = 0; j2 < 4; ++j2) {
      int col = bn + tn + j2;
      float v = acc[i2][j2] + bias[col];
      if (mode == 0)
        stF(&C[(size_t)row * DM + col], v);
      else
        stF(&C[((size_t)(col >> 6) * SEQ + row) * HDM + (col & 63)], v);
    }
  }
}

// One block per (query row i, head h). 256 threads.
// scores[j] = (Q_i . K_j)/8 + Q_i . T[i-j+S-1]; softmax; out = p @ V.
__global__ __launch_bounds__(256) void attn_row(
    const bf16* __restrict__ Q, const bf16* __restrict__ K,
    const bf16* __restrict__ V, const float* __restrict__ T,
    bf16* __restrict__ O)
{
  const int i = blockIdx.x;
  const int h = blockIdx.y;
  const int tid = threadIdx.x;
  __shared__ float q[HDM];
  __shared__ float p[SEQ];
  __shared__ float redA[4], redB[4];
  __shared__ float sred[4][HDM];

  const bf16* Qr = Q + ((size_t)h * SEQ + i) * HDM;
  if (tid < HDM) q[tid] = __bfloat162float(Qr[tid]);
  __syncthreads();

  // Phase 1: all 2048 scores into LDS
  const bf16* Kh = K + (size_t)h * SEQ * HDM;
  for (int j = tid; j < SEQ; j += 256) {
    const float4* Kr = (const float4*)(Kh + (size_t)j * HDM);          // bf16x8 chunks
    const float4* Tr = (const float4*)(T + (size_t)(i - j + SEQ - 1) * HDM); // f32x4 chunks
    float s1 = 0.f, s2 = 0.f;
#pragma unroll
    for (int t = 0; t < 8; ++t) {
      float4 kv = Kr[t];
      const __hip_bfloat162* kp = (const __hip_bfloat162*)&kv;
#pragma unroll
      for (int u = 0; u < 4; ++u) {
        float2 kf = __bfloat1622float2(kp[u]);
        s1 += q[t * 8 + u * 2] * kf.x + q[t * 8 + u * 2 + 1] * kf.y;
      }
    }
#pragma unroll
    for (int t = 0; t < 16; ++t) {
      float4 tv = Tr[t];
      s2 += q[t * 4 + 0] * tv.x + q[t * 4 + 1] * tv.y
          + q[t * 4 + 2] * tv.z + q[t * 4 + 3] * tv.w;
    }
    p[j] = s1 * 0.125f + s2;
  }
  __syncthreads();

  // Softmax max
  float m = -1e30f;
  for (int j = tid; j < SEQ; j += 256) m = fmaxf(m, p[j]);
#pragma unroll
  for (int off = 1; off < 64; off <<= 1) m = fmaxf(m, __shfl_xor(m, off, 64));
  if ((tid & 63) == 0) redA[tid >> 6] = m;
  __syncthreads();
  m = fmaxf(fmaxf(redA[0], redA[1]), fmaxf(redA[2], redA[3]));

  // exp + sum
  float lsum = 0.f;
  for (int j = tid; j < SEQ; j += 256) {
    float e = __expf(p[j] - m);
    p[j] = e;
    lsum += e;
  }
#pragma unroll
  for (int off = 1; off < 64; off <<= 1) lsum += __shfl_xor(lsum, off, 64);
  if ((tid & 63) == 0) redB[tid >> 6] = lsum;
  __syncthreads();
  const float l = redB[0] + redB[1] + redB[2] + redB[3];

  // Phase 2: out[d] = sum_j p[j] * V[j][d]; lane=d coalesced, 4 j-chunks
  const int d = tid & 63, c = tid >> 6;
  const bf16* Vh = V + (size_t)h * SEQ * HDM;
  float acc = 0.f;
  for (int j = c * (SEQ / 4); j < (c + 1) * (SEQ / 4); ++j)
    acc += p[j] * __bfloat162float(Vh[(size_t)j * HDM + d]);
  sred[c][d] = acc;
  __syncthreads();
  if (tid < HDM) {
    float o = (sred[0][tid] + sred[1][tid] + sred[2][tid] + sred[3][tid]) / l;
    O[(size_t)i * DM + h * HDM + tid] = __float2bfloat16(o);
  }
}

extern "C" void kernel_launch(void* const* d_in, const int* in_sizes, int n_in,
                              void* d_out, int out_size, void* d_ws, size_t ws_size,
                              hipStream_t stream) {
  const float* x   = (const float*)d_in[0];
  const float* Wq  = (const float*)d_in[1];
  const float* bq  = (const float*)d_in[2];
  const float* Wk  = (const float*)d_in[3];
  const float* bk  = (const float*)d_in[4];
  const float* Wv  = (const float*)d_in[5];
  const float* bv  = (const float*)d_in[6];
  const float* Wo  = (const float*)d_in[7];
  const float* bo  = (const float*)d_in[8];
  const float* rel = (const float*)d_in[9];
  float* out = (float*)d_out;

  // workspace: Q,K,V head-major [H][S][64] + attn out [S][D], bf16 (16 MB)
  bf16* qws = (bf16*)d_ws;
  bf16* kws = qws + (size_t)SEQ * DM;
  bf16* vws = kws + (size_t)SEQ * DM;
  bf16* ows = vws + (size_t)SEQ * DM;

  dim3 g(DM / 64, SEQ / 64);
  gemm_bias<float, bf16><<<g, 256, 0, stream>>>(x, Wq, bq, qws, 1);
  gemm_bias<float, bf16><<<g, 256, 0, stream>>>(x, Wk, bk, kws, 1);
  gemm_bias<float, bf16><<<g, 256, 0, stream>>>(x, Wv, bv, vws, 1);
  attn_row<<<dim3(SEQ, NH), 256, 0, stream>>>(qws, kws, vws, rel, ows);
  gemm_bias<bf16, float><<<g, 256, 0, stream>>>(ows, Wo, bo, out, 0);
}

// Round 3
// 463.335 us; speedup vs baseline: 10.0506x; 10.0506x over previous
//
#include <hip/hip_runtime.h>
#include <hip/hip_bf16.h>

#define SEQ 2048
#define DM  1024
#define NH  16
#define HDM 64

typedef __hip_bfloat16 bf16;
typedef __bf16 bhalf8 __attribute__((ext_vector_type(8)));
typedef float floatx4 __attribute__((ext_vector_type(4)));

__device__ __forceinline__ float toF(float x) { return x; }
__device__ __forceinline__ float toF(bf16 x)  { return __bfloat162float(x); }
__device__ __forceinline__ void  stF(float* p, float v) { *p = v; }
__device__ __forceinline__ void  stF(bf16* p, float v)  { *p = __float2bfloat16(v); }

// C[2048,1024] = A[2048,1024] @ B[1024,1024] + bias
// mode 0: C row-major [S, D]
// mode 1: C head-major [H][S][64]: C[((col>>6)*SEQ + row)*64 + (col&63)]
// mode 2: C transposed [D][S]:     C[col*SEQ + row]
template <typename TA, typename TC>
__global__ __launch_bounds__(256) void gemm_bias(
    const TA* __restrict__ A, const float* __restrict__ B,
    const float* __restrict__ bias, TC* __restrict__ C, int mode)
{
  __shared__ __align__(16) float As[16][68];  // [k][m]
  __shared__ __align__(16) float Bs[16][68];  // [k][n]
  const int bm = blockIdx.y * 64;
  const int bn = blockIdx.x * 64;
  const int tid = threadIdx.x;
  const int tm = (tid >> 4) << 2;
  const int tn = (tid & 15) << 2;
  float acc[4][4] = {};
  for (int k0 = 0; k0 < DM; k0 += 16) {
#pragma unroll
    for (int r = 0; r < 4; ++r) {
      int idx = tid + r * 256;            // 0..1023
      int m = idx >> 4, k = idx & 15;     // A tile 64m x 16k
      As[k][m] = toF(A[(size_t)(bm + m) * DM + (k0 + k)]);
      int kk = idx >> 6, n = idx & 63;    // B tile 16k x 64n
      Bs[kk][n] = B[(size_t)(k0 + kk) * DM + (bn + n)];
    }
    __syncthreads();
#pragma unroll
    for (int k = 0; k < 16; ++k) {
      float4 a4 = *(const float4*)&As[k][tm];
      float4 b4 = *(const float4*)&Bs[k][tn];
      float av[4] = {a4.x, a4.y, a4.z, a4.w};
      float bv[4] = {b4.x, b4.y, b4.z, b4.w};
#pragma unroll
      for (int i2 = 0; i2 < 4; ++i2)
#pragma unroll
        for (int j2 = 0; j2 < 4; ++j2)
          acc[i2][j2] += av[i2] * bv[j2];
    }
    __syncthreads();
  }
#pragma unroll
  for (int i2 = 0; i2 < 4; ++i2) {
    int row = bm + tm + i2;
#pragma unroll
    for (int j2 = 0; j2 < 4; ++j2) {
      int col = bn + tn + j2;
      float v = acc[i2][j2] + bias[col];
      if (mode == 0)
        stF(&C[(size_t)row * DM + col], v);
      else if (mode == 1)
        stF(&C[((size_t)(col >> 6) * SEQ + row) * HDM + (col & 63)], v);
      else
        stF(&C[(size_t)col * SEQ + row], v);
    }
  }
}

// Flash attention with relative-position scores.
// Grid: (SEQ/64, NH), 256 threads (4 waves). Q,K head-major [H][S][64] bf16;
// Vt transposed [D][S] bf16 (row h*64+d); T raw f32 [4095][64]; O bf16 [S][D].
__global__ __launch_bounds__(256) void attn_flash(
    const bf16* __restrict__ Q, const bf16* __restrict__ K,
    const bf16* __restrict__ Vt, const float* __restrict__ T,
    bf16* __restrict__ O)
{
  const int i0   = blockIdx.x * 64;
  const int h    = blockIdx.y;
  const int tid  = threadIdx.x;
  const int lane = tid & 63;
  const int wrow = (tid >> 6) * 16;   // wave's 16-row slice of the Q tile
  const int ln15 = lane & 15;
  const int quad = lane >> 4;

  __shared__ __align__(16) unsigned char smem[79104];
  bf16*  Qs  = (bf16*)smem;                // [64][72]
  bf16*  Ks  = (bf16*)(smem + 9216);       // [64][72]
  bf16*  Vs  = (bf16*)(smem + 18432);      // [64][72], [d][j]
  bf16*  Ts  = (bf16*)(smem + 27648);      // [128][72]
  bf16*  Ps  = (bf16*)(smem + 27648);      // [64][72], overlaps Ts (barriered)
  float* S2s = (float*)(smem + 46080);     // [64][129]

  const bf16* Qg = Q  + ((size_t)h * SEQ + i0) * HDM;
  const bf16* Kg = K  + (size_t)h * SEQ * HDM;
  const bf16* Vg = Vt + (size_t)h * HDM * SEQ;

  // stage Q tile (once)
#pragma unroll
  for (int t = 0; t < 2; ++t) {
    int id = tid + t * 256;
    int r = id >> 3, c = (id & 7) * 8;
    *(float4*)&Qs[r * 72 + c] = *(const float4*)&Qg[(size_t)r * HDM + c];
  }
  __syncthreads();

  const bhalf8 aq0 = *(bhalf8*)&Qs[(wrow + ln15) * 72 + quad * 8];
  const bhalf8 aq1 = *(bhalf8*)&Qs[(wrow + ln15) * 72 + quad * 8 + 32];

  floatx4 o[4];
  float mrow[4], lrow[4];
#pragma unroll
  for (int c = 0; c < 4; ++c) o[c] = (floatx4){0.f, 0.f, 0.f, 0.f};
#pragma unroll
  for (int r = 0; r < 4; ++r) { mrow[r] = -1e30f; lrow[r] = 0.f; }

  for (int jt = 0; jt < 32; ++jt) {
    const int j0 = jt * 64;
    const int rbase = i0 - j0 + SEQ - HDM;   // in [0, 3968]
    __syncthreads();   // protect Ks/Vs/Ts(Ps) from prior-iteration readers
    // stage K, V tiles (bf16x8 chunks, 2 each)
#pragma unroll
    for (int t = 0; t < 2; ++t) {
      int id = tid + t * 256;
      int r = id >> 3, c = (id & 7) * 8;
      *(float4*)&Ks[r * 72 + c] = *(const float4*)&Kg[(size_t)(j0 + r) * HDM + c];
      *(float4*)&Vs[r * 72 + c] = *(const float4*)&Vg[(size_t)r * SEQ + j0 + c];
    }
    // stage T band, f32 -> bf16 (4 chunks)
#pragma unroll
    for (int t = 0; t < 4; ++t) {
      int id = tid + t * 256;
      int r = id >> 3, c = (id & 7) * 8;
      int sr = rbase + r; if (sr > 2 * SEQ - 2) sr = 2 * SEQ - 2;  // row 127 pad
      const float* src = T + (size_t)sr * HDM + c;
      union { bf16 hh[8]; float4 v; } u;
#pragma unroll
      for (int e = 0; e < 8; ++e) u.hh[e] = __float2bfloat16(src[e]);
      *(float4*)&Ts[r * 72 + c] = u.v;
    }
    __syncthreads();

    // S2 = Q_tile @ T_band^T : 16x128 per wave (wave-private LDS region)
#pragma unroll
    for (int ct = 0; ct < 8; ++ct) {
      bhalf8 b0 = *(bhalf8*)&Ts[(ct * 16 + ln15) * 72 + quad * 8];
      bhalf8 b1 = *(bhalf8*)&Ts[(ct * 16 + ln15) * 72 + quad * 8 + 32];
      floatx4 a = (floatx4){0.f, 0.f, 0.f, 0.f};
      a = __builtin_amdgcn_mfma_f32_16x16x32_bf16(aq0, b0, a, 0, 0, 0);
      a = __builtin_amdgcn_mfma_f32_16x16x32_bf16(aq1, b1, a, 0, 0, 0);
#pragma unroll
      for (int r = 0; r < 4; ++r)
        S2s[(wrow + quad * 4 + r) * 129 + ct * 16 + ln15] = a[r];
    }
    __syncthreads();   // all waves done with Ts -> Ps region reusable

    // S1 = Q K^T, add gathered rel band, online softmax
    float sc[4][4];
#pragma unroll
    for (int ct = 0; ct < 4; ++ct) {
      bhalf8 b0 = *(bhalf8*)&Ks[(ct * 16 + ln15) * 72 + quad * 8];
      bhalf8 b1 = *(bhalf8*)&Ks[(ct * 16 + ln15) * 72 + quad * 8 + 32];
      floatx4 a = (floatx4){0.f, 0.f, 0.f, 0.f};
      a = __builtin_amdgcn_mfma_f32_16x16x32_bf16(aq0, b0, a, 0, 0, 0);
      a = __builtin_amdgcn_mfma_f32_16x16x32_bf16(aq1, b1, a, 0, 0, 0);
#pragma unroll
      for (int r = 0; r < 4; ++r) {
        int row = wrow + quad * 4 + r;          // 0..63 within Q tile
        int col = ct * 16 + ln15;               // 0..63 within K tile
        sc[ct][r] = a[r] * 0.125f + S2s[row * 129 + (row - col + 63)];
      }
    }
#pragma unroll
    for (int r = 0; r < 4; ++r) {
      float tm = fmaxf(fmaxf(sc[0][r], sc[1][r]), fmaxf(sc[2][r], sc[3][r]));
      tm = fmaxf(tm, __shfl_xor(tm, 1));
      tm = fmaxf(tm, __shfl_xor(tm, 2));
      tm = fmaxf(tm, __shfl_xor(tm, 4));
      tm = fmaxf(tm, __shfl_xor(tm, 8));
      float mn = fmaxf(mrow[r], tm);
      float alpha = __expf(mrow[r] - mn);
      mrow[r] = mn;
      float rs = 0.f;
#pragma unroll
      for (int ct = 0; ct < 4; ++ct) {
        float p = __expf(sc[ct][r] - mn);
        sc[ct][r] = p;
        rs += p;
      }
      rs += __shfl_xor(rs, 1); rs += __shfl_xor(rs, 2);
      rs += __shfl_xor(rs, 4); rs += __shfl_xor(rs, 8);
      lrow[r] = lrow[r] * alpha + rs;
#pragma unroll
      for (int ct = 0; ct < 4; ++ct) o[ct][r] *= alpha;
    }
    // P: C-layout regs -> LDS (wave-private rows) -> A-layout frags
#pragma unroll
    for (int ct = 0; ct < 4; ++ct)
#pragma unroll
      for (int r = 0; r < 4; ++r)
        Ps[(wrow + quad * 4 + r) * 72 + ct * 16 + ln15] = __float2bfloat16(sc[ct][r]);

    bhalf8 ap0 = *(bhalf8*)&Ps[(wrow + ln15) * 72 + quad * 8];
    bhalf8 ap1 = *(bhalf8*)&Ps[(wrow + ln15) * 72 + quad * 8 + 32];
#pragma unroll
    for (int ct = 0; ct < 4; ++ct) {
      bhalf8 b0 = *(bhalf8*)&Vs[(ct * 16 + ln15) * 72 + quad * 8];
      bhalf8 b1 = *(bhalf8*)&Vs[(ct * 16 + ln15) * 72 + quad * 8 + 32];
      o[ct] = __builtin_amdgcn_mfma_f32_16x16x32_bf16(ap0, b0, o[ct], 0, 0, 0);
      o[ct] = __builtin_amdgcn_mfma_f32_16x16x32_bf16(ap1, b1, o[ct], 0, 0, 0);
    }
  }

  // epilogue: O /= l, write [S][D] bf16
#pragma unroll
  for (int r = 0; r < 4; ++r) {
    float inv = 1.f / lrow[r];
    int row = i0 + wrow + quad * 4 + r;
#pragma unroll
    for (int ct = 0; ct < 4; ++ct)
      O[(size_t)row * DM + h * HDM + ct * 16 + ln15] =
          __float2bfloat16(o[ct][r] * inv);
  }
}

extern "C" void kernel_launch(void* const* d_in, const int* in_sizes, int n_in,
                              void* d_out, int out_size, void* d_ws, size_t ws_size,
                              hipStream_t stream) {
  const float* x   = (const float*)d_in[0];
  const float* Wq  = (const float*)d_in[1];
  const float* bq  = (const float*)d_in[2];
  const float* Wk  = (const float*)d_in[3];
  const float* bk  = (const float*)d_in[4];
  const float* Wv  = (const float*)d_in[5];
  const float* bv  = (const float*)d_in[6];
  const float* Wo  = (const float*)d_in[7];
  const float* bo  = (const float*)d_in[8];
  const float* rel = (const float*)d_in[9];
  float* out = (float*)d_out;

  // workspace: Q,K head-major [H][S][64]; Vt [D][S]; attn out [S][D]; bf16
  bf16* qws = (bf16*)d_ws;
  bf16* kws = qws + (size_t)SEQ * DM;
  bf16* vws = kws + (size_t)SEQ * DM;
  bf16* ows = vws + (size_t)SEQ * DM;

  dim3 g(DM / 64, SEQ / 64);
  gemm_bias<float, bf16><<<g, 256, 0, stream>>>(x, Wq, bq, qws, 1);
  gemm_bias<float, bf16><<<g, 256, 0, stream>>>(x, Wk, bk, kws, 1);
  gemm_bias<float, bf16><<<g, 256, 0, stream>>>(x, Wv, bv, vws, 2);
  attn_flash<<<dim3(SEQ / 64, NH), 256, 0, stream>>>(qws, kws, vws, rel, ows);
  gemm_bias<bf16, float><<<g, 256, 0, stream>>>(ows, Wo, bo, out, 0);
}

// Round 4
// 250.945 us; speedup vs baseline: 18.5570x; 1.8464x over previous
//
#include <hip/hip_runtime.h>
#include <hip/hip_bf16.h>

#define SEQ 2048
#define DM  1024
#define NH  16
#define HDM 64

typedef __hip_bfloat16 bf16;
typedef __bf16 bhalf8 __attribute__((ext_vector_type(8)));
typedef float floatx4 __attribute__((ext_vector_type(4)));

__device__ __forceinline__ void async_cp16(const void* g, void* l) {
  __builtin_amdgcn_global_load_lds(
      (const __attribute__((address_space(1))) void*)g,
      (__attribute__((address_space(3))) void*)l, 16, 0, 0);
}

// ---- convert: x f32 -> bf16 [2048*1024]; rel f32 -> bf16 padded [4096][64]
__global__ __launch_bounds__(256) void convert_inputs(
    const float* __restrict__ x, const float* __restrict__ T,
    bf16* __restrict__ xbf, bf16* __restrict__ Tbf)
{
  const int c = blockIdx.x * 256 + threadIdx.x;
  if (c < 524288) {                       // x: 2M elems, 4 per thread
    float4 v = *(const float4*)&x[(size_t)c * 4];
    union { bf16 h[4]; float2 f; } u;
    u.h[0] = __float2bfloat16(v.x); u.h[1] = __float2bfloat16(v.y);
    u.h[2] = __float2bfloat16(v.z); u.h[3] = __float2bfloat16(v.w);
    *(float2*)&xbf[(size_t)c * 4] = u.f;
  } else {                                 // T: 4096*64 padded (row 4095 dup)
    int ct = c - 524288;                   // [0, 65536)
    union { bf16 h[4]; float2 f; } u;
#pragma unroll
    for (int e = 0; e < 4; ++e) {
      int se = ct * 4 + e;
      if (se >= 4095 * 64) se -= 64;
      u.h[e] = __float2bfloat16(T[se]);
    }
    *(float2*)&Tbf[(size_t)ct * 4] = u.f;
  }
}

// ---- transpose weights: W f32 [k][n] -> Wt bf16 [n][k]; z selects matrix
__global__ __launch_bounds__(256) void transpose_w(
    const float* __restrict__ W0, const float* __restrict__ W1,
    const float* __restrict__ W2, const float* __restrict__ W3,
    bf16* __restrict__ WtBase)
{
  __shared__ float tile[64][69];
  const int z = blockIdx.z;
  const float* W = (z == 0) ? W0 : (z == 1) ? W1 : (z == 2) ? W2 : W3;
  bf16* Wt = WtBase + (size_t)z * DM * DM;
  const int kb = blockIdx.x * 64, nb = blockIdx.y * 64;
  const int tid = threadIdx.x;
  const int r = tid >> 4, c4 = (tid & 15) * 4;
#pragma unroll
  for (int rr = 0; rr < 4; ++rr) {
    float4 v = *(const float4*)&W[(size_t)(kb + rr * 16 + r) * DM + nb + c4];
    tile[rr * 16 + r][c4 + 0] = v.x; tile[rr * 16 + r][c4 + 1] = v.y;
    tile[rr * 16 + r][c4 + 2] = v.z; tile[rr * 16 + r][c4 + 3] = v.w;
  }
  __syncthreads();
  const int w = tid >> 6, l = tid & 63;
#pragma unroll
  for (int i = 0; i < 16; ++i) {
    int n = nb + w * 16 + i;
    Wt[(size_t)n * DM + kb + l] = __float2bfloat16(tile[l][w * 16 + i]);
  }
}

// ---- MFMA GEMM core: acc[4][4] += A[128x1024] tile @ Bt[n][k]^T tile
__device__ __forceinline__ void gemm_core(
    const bf16* __restrict__ A, const bf16* __restrict__ Bt,
    bf16* As, bf16* Bs, int bm, int bn, floatx4 (&acc)[4][4])
{
  const int tid = threadIdx.x;
  const int lane = tid & 63;
  const int w = tid >> 6;
  const int wx = w & 1, wy = w >> 1;
  const int ln15 = lane & 15, quad = lane >> 4;

  for (int k0 = 0; k0 < DM; k0 += 32) {
#pragma unroll
    for (int t = 0; t < 2; ++t) {
      int cbase = w * 128 + t * 64;        // wave-uniform chunk base
      int c = cbase + lane;                // 16B chunk id, 512 total
      int row = c >> 2, col = (c & 3) * 8;
      async_cp16(A  + (size_t)(bm + row) * DM + k0 + col, As + cbase * 8);
      async_cp16(Bt + (size_t)(bn + row) * DM + k0 + col, Bs + cbase * 8);
    }
    __syncthreads();                        // drains vmcnt before reads
    bhalf8 af[4], bfr[4];
#pragma unroll
    for (int i = 0; i < 4; ++i)
      af[i] = *(bhalf8*)&As[(wy * 64 + i * 16 + ln15) * 32 + quad * 8];
#pragma unroll
    for (int j = 0; j < 4; ++j)
      bfr[j] = *(bhalf8*)&Bs[(wx * 64 + j * 16 + ln15) * 32 + quad * 8];
#pragma unroll
    for (int i = 0; i < 4; ++i)
#pragma unroll
      for (int j = 0; j < 4; ++j)
        acc[i][j] = __builtin_amdgcn_mfma_f32_16x16x32_bf16(af[i], bfr[j], acc[i][j], 0, 0, 0);
    __syncthreads();                        // protect LDS before next stage
  }
}

// ---- QKV projection, batched z=0,1,2. Out: z<2 head-major; z==2 transposed [D][S]
__global__ __launch_bounds__(256) void gemm_qkv(
    const bf16* __restrict__ A, const bf16* __restrict__ Wt3,
    const float* __restrict__ bq, const float* __restrict__ bk,
    const float* __restrict__ bv, bf16* __restrict__ outbase)
{
  __shared__ __align__(16) bf16 As[128 * 32];
  __shared__ __align__(16) bf16 Bs[128 * 32];
  const int z = blockIdx.z;
  const bf16* Bt = Wt3 + (size_t)z * DM * DM;
  const float* bias = (z == 0) ? bq : (z == 1) ? bk : bv;
  bf16* C = outbase + (size_t)z * SEQ * DM;
  const int bm = blockIdx.y * 128, bn = blockIdx.x * 128;
  floatx4 acc[4][4];
#pragma unroll
  for (int i = 0; i < 4; ++i)
#pragma unroll
    for (int j = 0; j < 4; ++j) acc[i][j] = (floatx4){0.f, 0.f, 0.f, 0.f};
  gemm_core(A, Bt, As, Bs, bm, bn, acc);

  const int lane = threadIdx.x & 63;
  const int w = threadIdx.x >> 6;
  const int wx = w & 1, wy = w >> 1;
  const int ln15 = lane & 15, quad = lane >> 4;
#pragma unroll
  for (int i = 0; i < 4; ++i)
#pragma unroll
    for (int j = 0; j < 4; ++j) {
      int col = bn + wx * 64 + j * 16 + ln15;
      float bv_ = bias[col];
#pragma unroll
      for (int r = 0; r < 4; ++r) {
        int row = bm + wy * 64 + i * 16 + quad * 4 + r;
        float v = acc[i][j][r] + bv_;
        if (z < 2)
          C[((size_t)(col >> 6) * SEQ + row) * HDM + (col & 63)] = __float2bfloat16(v);
        else
          C[(size_t)col * SEQ + row] = __float2bfloat16(v);
      }
    }
}

// ---- output projection: f32 out row-major
__global__ __launch_bounds__(256) void gemm_out(
    const bf16* __restrict__ A, const bf16* __restrict__ Bt,
    const float* __restrict__ bias, float* __restrict__ C)
{
  __shared__ __align__(16) bf16 As[128 * 32];
  __shared__ __align__(16) bf16 Bs[128 * 32];
  const int bm = blockIdx.y * 128, bn = blockIdx.x * 128;
  floatx4 acc[4][4];
#pragma unroll
  for (int i = 0; i < 4; ++i)
#pragma unroll
    for (int j = 0; j < 4; ++j) acc[i][j] = (floatx4){0.f, 0.f, 0.f, 0.f};
  gemm_core(A, Bt, As, Bs, bm, bn, acc);

  const int lane = threadIdx.x & 63;
  const int w = threadIdx.x >> 6;
  const int wx = w & 1, wy = w >> 1;
  const int ln15 = lane & 15, quad = lane >> 4;
#pragma unroll
  for (int i = 0; i < 4; ++i)
#pragma unroll
    for (int j = 0; j < 4; ++j) {
      int col = bn + wx * 64 + j * 16 + ln15;
      float bv_ = bias[col];
#pragma unroll
      for (int r = 0; r < 4; ++r) {
        int row = bm + wy * 64 + i * 16 + quad * 4 + r;
        C[(size_t)row * DM + col] = acc[i][j][r] + bv_;
      }
    }
}

// ---- Flash attention with relative-position scores (Tb pre-converted bf16).
__global__ __launch_bounds__(256) void attn_flash(
    const bf16* __restrict__ Q, const bf16* __restrict__ K,
    const bf16* __restrict__ Vt, const bf16* __restrict__ Tb,
    bf16* __restrict__ O)
{
  const int i0   = blockIdx.x * 64;
  const int h    = blockIdx.y;
  const int tid  = threadIdx.x;
  const int lane = tid & 63;
  const int wrow = (tid >> 6) * 16;
  const int ln15 = lane & 15;
  const int quad = lane >> 4;

  __shared__ __align__(16) unsigned char smem[79104];
  bf16*  Qs  = (bf16*)smem;                // [64][72]
  bf16*  Ks  = (bf16*)(smem + 9216);       // [64][72]
  bf16*  Vs  = (bf16*)(smem + 18432);      // [64][72], [d][j]
  bf16*  Ts  = (bf16*)(smem + 27648);      // [128][72]
  bf16*  Ps  = (bf16*)(smem + 27648);      // [64][72], overlaps Ts (barriered)
  float* S2s = (float*)(smem + 46080);     // [64][129]

  const bf16* Qg = Q  + ((size_t)h * SEQ + i0) * HDM;
  const bf16* Kg = K  + (size_t)h * SEQ * HDM;
  const bf16* Vg = Vt + (size_t)h * HDM * SEQ;

#pragma unroll
  for (int t = 0; t < 2; ++t) {
    int id = tid + t * 256;
    int r = id >> 3, c = (id & 7) * 8;
    *(float4*)&Qs[r * 72 + c] = *(const float4*)&Qg[(size_t)r * HDM + c];
  }
  __syncthreads();

  const bhalf8 aq0 = *(bhalf8*)&Qs[(wrow + ln15) * 72 + quad * 8];
  const bhalf8 aq1 = *(bhalf8*)&Qs[(wrow + ln15) * 72 + quad * 8 + 32];

  floatx4 o[4];
  float mrow[4], lrow[4];
#pragma unroll
  for (int c = 0; c < 4; ++c) o[c] = (floatx4){0.f, 0.f, 0.f, 0.f};
#pragma unroll
  for (int r = 0; r < 4; ++r) { mrow[r] = -1e30f; lrow[r] = 0.f; }

  for (int jt = 0; jt < 32; ++jt) {
    const int j0 = jt * 64;
    const int rbase = i0 - j0 + SEQ - HDM;   // in [0, 3968]
    __syncthreads();
#pragma unroll
    for (int t = 0; t < 2; ++t) {
      int id = tid + t * 256;
      int r = id >> 3, c = (id & 7) * 8;
      *(float4*)&Ks[r * 72 + c] = *(const float4*)&Kg[(size_t)(j0 + r) * HDM + c];
      *(float4*)&Vs[r * 72 + c] = *(const float4*)&Vg[(size_t)r * SEQ + j0 + c];
    }
#pragma unroll
    for (int t = 0; t < 4; ++t) {
      int id = tid + t * 256;
      int r = id >> 3, c = (id & 7) * 8;
      *(float4*)&Ts[r * 72 + c] = *(const float4*)&Tb[(size_t)(rbase + r) * HDM + c];
    }
    __syncthreads();

    // S2 = Q_tile @ T_band^T : 16x128 per wave (wave-private LDS region)
#pragma unroll
    for (int ct = 0; ct < 8; ++ct) {
      bhalf8 b0 = *(bhalf8*)&Ts[(ct * 16 + ln15) * 72 + quad * 8];
      bhalf8 b1 = *(bhalf8*)&Ts[(ct * 16 + ln15) * 72 + quad * 8 + 32];
      floatx4 a = (floatx4){0.f, 0.f, 0.f, 0.f};
      a = __builtin_amdgcn_mfma_f32_16x16x32_bf16(aq0, b0, a, 0, 0, 0);
      a = __builtin_amdgcn_mfma_f32_16x16x32_bf16(aq1, b1, a, 0, 0, 0);
#pragma unroll
      for (int r = 0; r < 4; ++r)
        S2s[(wrow + quad * 4 + r) * 129 + ct * 16 + ln15] = a[r];
    }
    __syncthreads();

    // S1 = Q K^T, add gathered rel band, online softmax
    float sc[4][4];
#pragma unroll
    for (int ct = 0; ct < 4; ++ct) {
      bhalf8 b0 = *(bhalf8*)&Ks[(ct * 16 + ln15) * 72 + quad * 8];
      bhalf8 b1 = *(bhalf8*)&Ks[(ct * 16 + ln15) * 72 + quad * 8 + 32];
      floatx4 a = (floatx4){0.f, 0.f, 0.f, 0.f};
      a = __builtin_amdgcn_mfma_f32_16x16x32_bf16(aq0, b0, a, 0, 0, 0);
      a = __builtin_amdgcn_mfma_f32_16x16x32_bf16(aq1, b1, a, 0, 0, 0);
#pragma unroll
      for (int r = 0; r < 4; ++r) {
        int row = wrow + quad * 4 + r;
        int col = ct * 16 + ln15;
        sc[ct][r] = a[r] * 0.125f + S2s[row * 129 + (row - col + 63)];
      }
    }
#pragma unroll
    for (int r = 0; r < 4; ++r) {
      float tm = fmaxf(fmaxf(sc[0][r], sc[1][r]), fmaxf(sc[2][r], sc[3][r]));
      tm = fmaxf(tm, __shfl_xor(tm, 1));
      tm = fmaxf(tm, __shfl_xor(tm, 2));
      tm = fmaxf(tm, __shfl_xor(tm, 4));
      tm = fmaxf(tm, __shfl_xor(tm, 8));
      float mn = fmaxf(mrow[r], tm);
      float alpha = __expf(mrow[r] - mn);
      mrow[r] = mn;
      float rs = 0.f;
#pragma unroll
      for (int ct = 0; ct < 4; ++ct) {
        float p = __expf(sc[ct][r] - mn);
        sc[ct][r] = p;
        rs += p;
      }
      rs += __shfl_xor(rs, 1); rs += __shfl_xor(rs, 2);
      rs += __shfl_xor(rs, 4); rs += __shfl_xor(rs, 8);
      lrow[r] = lrow[r] * alpha + rs;
#pragma unroll
      for (int ct = 0; ct < 4; ++ct) o[ct][r] *= alpha;
    }
#pragma unroll
    for (int ct = 0; ct < 4; ++ct)
#pragma unroll
      for (int r = 0; r < 4; ++r)
        Ps[(wrow + quad * 4 + r) * 72 + ct * 16 + ln15] = __float2bfloat16(sc[ct][r]);

    bhalf8 ap0 = *(bhalf8*)&Ps[(wrow + ln15) * 72 + quad * 8];
    bhalf8 ap1 = *(bhalf8*)&Ps[(wrow + ln15) * 72 + quad * 8 + 32];
#pragma unroll
    for (int ct = 0; ct < 4; ++ct) {
      bhalf8 b0 = *(bhalf8*)&Vs[(ct * 16 + ln15) * 72 + quad * 8];
      bhalf8 b1 = *(bhalf8*)&Vs[(ct * 16 + ln15) * 72 + quad * 8 + 32];
      o[ct] = __builtin_amdgcn_mfma_f32_16x16x32_bf16(ap0, b0, o[ct], 0, 0, 0);
      o[ct] = __builtin_amdgcn_mfma_f32_16x16x32_bf16(ap1, b1, o[ct], 0, 0, 0);
    }
  }

#pragma unroll
  for (int r = 0; r < 4; ++r) {
    float inv = 1.f / lrow[r];
    int row = i0 + wrow + quad * 4 + r;
#pragma unroll
    for (int ct = 0; ct < 4; ++ct)
      O[(size_t)row * DM + h * HDM + ct * 16 + ln15] =
          __float2bfloat16(o[ct][r] * inv);
  }
}

extern "C" void kernel_launch(void* const* d_in, const int* in_sizes, int n_in,
                              void* d_out, int out_size, void* d_ws, size_t ws_size,
                              hipStream_t stream) {
  const float* x   = (const float*)d_in[0];
  const float* Wq  = (const float*)d_in[1];
  const float* bq  = (const float*)d_in[2];
  const float* Wk  = (const float*)d_in[3];
  const float* bk  = (const float*)d_in[4];
  const float* Wv  = (const float*)d_in[5];
  const float* bv  = (const float*)d_in[6];
  const float* Wo  = (const float*)d_in[7];
  const float* bo  = (const float*)d_in[8];
  const float* rel = (const float*)d_in[9];
  float* out = (float*)d_out;

  const size_t SD = (size_t)SEQ * DM;      // 2M elems
  bf16* qws = (bf16*)d_ws;                 // [H][S][64]
  bf16* kws = qws + SD;                    // [H][S][64]
  bf16* vws = kws + SD;                    // Vt [D][S]
  bf16* ows = vws + SD;                    // [S][D]
  bf16* xbf = ows + SD;                    // [S][D]
  bf16* wt  = xbf + SD;                    // 4 x [n][k] (q,k,v,o)
  bf16* tbf = wt + 4 * (size_t)DM * DM;    // [4096][64]

  convert_inputs<<<2304, 256, 0, stream>>>(x, rel, xbf, tbf);
  transpose_w<<<dim3(16, 16, 4), 256, 0, stream>>>(Wq, Wk, Wv, Wo, wt);
  gemm_qkv<<<dim3(8, 16, 3), 256, 0, stream>>>(xbf, wt, bq, bk, bv, qws);
  attn_flash<<<dim3(SEQ / 64, NH), 256, 0, stream>>>(qws, kws, vws, tbf, ows);
  gemm_out<<<dim3(8, 16), 256, 0, stream>>>(ows, wt + 3 * (size_t)DM * DM, bo, out);
}

// Round 6
// 249.933 us; speedup vs baseline: 18.6322x; 1.0041x over previous
//
#include <hip/hip_runtime.h>
#include <hip/hip_bf16.h>

#define SEQ 2048
#define DM  1024
#define NH  16
#define HDM 64

typedef __hip_bfloat16 bf16;
typedef __bf16 bhalf8 __attribute__((ext_vector_type(8)));
typedef float floatx4 __attribute__((ext_vector_type(4)));

__device__ __forceinline__ void async_cp16(const void* g, void* l) {
  __builtin_amdgcn_global_load_lds(
      (const __attribute__((address_space(1))) void*)g,
      (__attribute__((address_space(3))) void*)l, 16, 0, 0);
}

// ---- convert: x f32 -> bf16 [2048*1024]; rel f32 -> bf16 padded [4096][64]
__global__ __launch_bounds__(256) void convert_inputs(
    const float* __restrict__ x, const float* __restrict__ T,
    bf16* __restrict__ xbf, bf16* __restrict__ Tbf)
{
  const int c = blockIdx.x * 256 + threadIdx.x;
  if (c < 524288) {                       // x: 2M elems, 4 per thread
    float4 v = *(const float4*)&x[(size_t)c * 4];
    union { bf16 h[4]; float2 f; } u;
    u.h[0] = __float2bfloat16(v.x); u.h[1] = __float2bfloat16(v.y);
    u.h[2] = __float2bfloat16(v.z); u.h[3] = __float2bfloat16(v.w);
    *(float2*)&xbf[(size_t)c * 4] = u.f;
  } else {                                 // T: 4096*64 padded (row 4095 dup)
    int ct = c - 524288;                   // [0, 65536)
    union { bf16 h[4]; float2 f; } u;
#pragma unroll
    for (int e = 0; e < 4; ++e) {
      int se = ct * 4 + e;
      if (se >= 4095 * 64) se -= 64;
      u.h[e] = __float2bfloat16(T[se]);
    }
    *(float2*)&Tbf[(size_t)ct * 4] = u.f;
  }
}

// ---- transpose weights: W f32 [k][n] -> Wt bf16 [n][k]; z selects matrix
__global__ __launch_bounds__(256) void transpose_w(
    const float* __restrict__ W0, const float* __restrict__ W1,
    const float* __restrict__ W2, const float* __restrict__ W3,
    bf16* __restrict__ WtBase)
{
  __shared__ float tile[64][69];
  const int z = blockIdx.z;
  const float* W = (z == 0) ? W0 : (z == 1) ? W1 : (z == 2) ? W2 : W3;
  bf16* Wt = WtBase + (size_t)z * DM * DM;
  const int kb = blockIdx.x * 64, nb = blockIdx.y * 64;
  const int tid = threadIdx.x;
  const int r = tid >> 4, c4 = (tid & 15) * 4;
#pragma unroll
  for (int rr = 0; rr < 4; ++rr) {
    float4 v = *(const float4*)&W[(size_t)(kb + rr * 16 + r) * DM + nb + c4];
    tile[rr * 16 + r][c4 + 0] = v.x; tile[rr * 16 + r][c4 + 1] = v.y;
    tile[rr * 16 + r][c4 + 2] = v.z; tile[rr * 16 + r][c4 + 3] = v.w;
  }
  __syncthreads();
  const int w = tid >> 6, l = tid & 63;
#pragma unroll
  for (int i = 0; i < 16; ++i) {
    int n = nb + w * 16 + i;
    Wt[(size_t)n * DM + kb + l] = __float2bfloat16(tile[l][w * 16 + i]);
  }
}

// ---- MFMA GEMM core: acc[4][4] += A[128x1024] tile @ Bt[n][k]^T tile
__device__ __forceinline__ void gemm_core(
    const bf16* __restrict__ A, const bf16* __restrict__ Bt,
    bf16* As, bf16* Bs, int bm, int bn, floatx4 (&acc)[4][4])
{
  const int tid = threadIdx.x;
  const int lane = tid & 63;
  const int w = tid >> 6;
  const int wx = w & 1, wy = w >> 1;
  const int ln15 = lane & 15, quad = lane >> 4;

  for (int k0 = 0; k0 < DM; k0 += 32) {
#pragma unroll
    for (int t = 0; t < 2; ++t) {
      int cbase = w * 128 + t * 64;        // wave-uniform chunk base
      int c = cbase + lane;                // 16B chunk id, 512 total
      int row = c >> 2, col = (c & 3) * 8;
      async_cp16(A  + (size_t)(bm + row) * DM + k0 + col, As + cbase * 8);
      async_cp16(Bt + (size_t)(bn + row) * DM + k0 + col, Bs + cbase * 8);
    }
    __syncthreads();                        // drains vmcnt before reads
    bhalf8 af[4], bfr[4];
#pragma unroll
    for (int i = 0; i < 4; ++i)
      af[i] = *(bhalf8*)&As[(wy * 64 + i * 16 + ln15) * 32 + quad * 8];
#pragma unroll
    for (int j = 0; j < 4; ++j)
      bfr[j] = *(bhalf8*)&Bs[(wx * 64 + j * 16 + ln15) * 32 + quad * 8];
#pragma unroll
    for (int i = 0; i < 4; ++i)
#pragma unroll
      for (int j = 0; j < 4; ++j)
        acc[i][j] = __builtin_amdgcn_mfma_f32_16x16x32_bf16(af[i], bfr[j], acc[i][j], 0, 0, 0);
    __syncthreads();                        // protect LDS before next stage
  }
}

// ---- QKV projection, batched z=0,1,2. Out: z<2 head-major; z==2 transposed [D][S]
__global__ __launch_bounds__(256) void gemm_qkv(
    const bf16* __restrict__ A, const bf16* __restrict__ Wt3,
    const float* __restrict__ bq, const float* __restrict__ bk,
    const float* __restrict__ bv, bf16* __restrict__ outbase)
{
  __shared__ __align__(16) bf16 As[128 * 32];
  __shared__ __align__(16) bf16 Bs[128 * 32];
  const int z = blockIdx.z;
  const bf16* Bt = Wt3 + (size_t)z * DM * DM;
  const float* bias = (z == 0) ? bq : (z == 1) ? bk : bv;
  bf16* C = outbase + (size_t)z * SEQ * DM;
  const int bm = blockIdx.y * 128, bn = blockIdx.x * 128;
  floatx4 acc[4][4];
#pragma unroll
  for (int i = 0; i < 4; ++i)
#pragma unroll
    for (int j = 0; j < 4; ++j) acc[i][j] = (floatx4){0.f, 0.f, 0.f, 0.f};
  gemm_core(A, Bt, As, Bs, bm, bn, acc);

  const int lane = threadIdx.x & 63;
  const int w = threadIdx.x >> 6;
  const int wx = w & 1, wy = w >> 1;
  const int ln15 = lane & 15, quad = lane >> 4;
#pragma unroll
  for (int i = 0; i < 4; ++i)
#pragma unroll
    for (int j = 0; j < 4; ++j) {
      int col = bn + wx * 64 + j * 16 + ln15;
      float bv_ = bias[col];
#pragma unroll
      for (int r = 0; r < 4; ++r) {
        int row = bm + wy * 64 + i * 16 + quad * 4 + r;
        float v = acc[i][j][r] + bv_;
        if (z < 2)
          C[((size_t)(col >> 6) * SEQ + row) * HDM + (col & 63)] = __float2bfloat16(v);
        else
          C[(size_t)col * SEQ + row] = __float2bfloat16(v);
      }
    }
}

// ---- output projection: f32 out row-major
__global__ __launch_bounds__(256) void gemm_out(
    const bf16* __restrict__ A, const bf16* __restrict__ Bt,
    const float* __restrict__ bias, float* __restrict__ C)
{
  __shared__ __align__(16) bf16 As[128 * 32];
  __shared__ __align__(16) bf16 Bs[128 * 32];
  const int bm = blockIdx.y * 128, bn = blockIdx.x * 128;
  floatx4 acc[4][4];
#pragma unroll
  for (int i = 0; i < 4; ++i)
#pragma unroll
    for (int j = 0; j < 4; ++j) acc[i][j] = (floatx4){0.f, 0.f, 0.f, 0.f};
  gemm_core(A, Bt, As, Bs, bm, bn, acc);

  const int lane = threadIdx.x & 63;
  const int w = threadIdx.x >> 6;
  const int wx = w & 1, wy = w >> 1;
  const int ln15 = lane & 15, quad = lane >> 4;
#pragma unroll
  for (int i = 0; i < 4; ++i)
#pragma unroll
    for (int j = 0; j < 4; ++j) {
      int col = bn + wx * 64 + j * 16 + ln15;
      float bv_ = bias[col];
#pragma unroll
      for (int r = 0; r < 4; ++r) {
        int row = bm + wy * 64 + i * 16 + quad * 4 + r;
        C[(size_t)row * DM + col] = acc[i][j][r] + bv_;
      }
    }
}

// ---- Flash attention, key-split x2, f32 diagonal-scatter S2.
// LDS 53760 B -> 3 blocks/CU.
__global__ __launch_bounds__(256) void attn_flash(
    const bf16* __restrict__ Q, const bf16* __restrict__ K,
    const bf16* __restrict__ Vt, const bf16* __restrict__ Tb,
    bf16* __restrict__ Opart, float* __restrict__ ml)
{
  const int i0   = blockIdx.x * 64;
  const int h    = blockIdx.y;
  const int z    = blockIdx.z;
  const int tid  = threadIdx.x;
  const int lane = tid & 63;
  const int wrow = (tid >> 6) * 16;
  const int ln15 = lane & 15;
  const int quad = lane >> 4;

  __shared__ __align__(16) unsigned char smem[53760];
  bf16*  Ks  = (bf16*)smem;                 // [64][72]
  bf16*  Vs  = (bf16*)(smem + 9216);        // [64][72], [d][j]
  bf16*  Ts  = (bf16*)(smem + 18432);       // [128][72]
  bf16*  Ps  = (bf16*)(smem + 18432);       // [64][72], overlaps Ts (barriered)
  float* S2c = (float*)(smem + 36864);      // [64][66] f32, diagonal layout
  bf16*  Qs  = (bf16*)(smem + 36864);       // [64][72], overlaps S2c (pre-loop)

  const bf16* Qg = Q  + ((size_t)h * SEQ + i0) * HDM;
  const bf16* Kg = K  + (size_t)h * SEQ * HDM;
  const bf16* Vg = Vt + (size_t)h * HDM * SEQ;

#pragma unroll
  for (int t = 0; t < 2; ++t) {
    int id = tid + t * 256;
    int r = id >> 3, c = (id & 7) * 8;
    *(float4*)&Qs[r * 72 + c] = *(const float4*)&Qg[(size_t)r * HDM + c];
  }
  __syncthreads();

  const bhalf8 aq0 = *(bhalf8*)&Qs[(wrow + ln15) * 72 + quad * 8];
  const bhalf8 aq1 = *(bhalf8*)&Qs[(wrow + ln15) * 72 + quad * 8 + 32];

  floatx4 o[4];
  float mrow[4], lrow[4];
#pragma unroll
  for (int c = 0; c < 4; ++c) o[c] = (floatx4){0.f, 0.f, 0.f, 0.f};
#pragma unroll
  for (int r = 0; r < 4; ++r) { mrow[r] = -1e30f; lrow[r] = 0.f; }

  for (int jt = z * 16; jt < z * 16 + 16; ++jt) {
    const int j0 = jt * 64;
    const int rbase = i0 - j0 + SEQ - HDM;   // in [0, 3968]
    __syncthreads();   // staging regions safe (prev iter fully consumed)
#pragma unroll
    for (int t = 0; t < 2; ++t) {
      int id = tid + t * 256;
      int r = id >> 3, c = (id & 7) * 8;
      *(float4*)&Ks[r * 72 + c] = *(const float4*)&Kg[(size_t)(j0 + r) * HDM + c];
      *(float4*)&Vs[r * 72 + c] = *(const float4*)&Vg[(size_t)r * SEQ + j0 + c];
    }
#pragma unroll
    for (int t = 0; t < 4; ++t) {
      int id = tid + t * 256;
      int r = id >> 3, c = (id & 7) * 8;
      *(float4*)&Ts[r * 72 + c] = *(const float4*)&Tb[(size_t)(rbase + r) * HDM + c];
    }
    __syncthreads();

    // S2 = Q_tile @ T_band^T (16x128 per wave), scattered to diagonal layout:
    // element (row, t) -> S2c[row][row+63-t] (f32, exact), wave-private rows.
#pragma unroll
    for (int ct = 0; ct < 8; ++ct) {
      bhalf8 b0 = *(bhalf8*)&Ts[(ct * 16 + ln15) * 72 + quad * 8];
      bhalf8 b1 = *(bhalf8*)&Ts[(ct * 16 + ln15) * 72 + quad * 8 + 32];
      floatx4 a = (floatx4){0.f, 0.f, 0.f, 0.f};
      a = __builtin_amdgcn_mfma_f32_16x16x32_bf16(aq0, b0, a, 0, 0, 0);
      a = __builtin_amdgcn_mfma_f32_16x16x32_bf16(aq1, b1, a, 0, 0, 0);
#pragma unroll
      for (int r = 0; r < 4; ++r) {
        int row = wrow + quad * 4 + r;
        int col = row + 63 - (ct * 16 + ln15);
        if ((unsigned)col < 64u) S2c[row * 66 + col] = a[r];
      }
    }
    __syncthreads();   // all waves done with Ts -> Ps region reusable

    // S1 = Q K^T, add rel band (contiguous read), online softmax
    float sc[4][4];
#pragma unroll
    for (int ct = 0; ct < 4; ++ct) {
      bhalf8 b0 = *(bhalf8*)&Ks[(ct * 16 + ln15) * 72 + quad * 8];
      bhalf8 b1 = *(bhalf8*)&Ks[(ct * 16 + ln15) * 72 + quad * 8 + 32];
      floatx4 a = (floatx4){0.f, 0.f, 0.f, 0.f};
      a = __builtin_amdgcn_mfma_f32_16x16x32_bf16(aq0, b0, a, 0, 0, 0);
      a = __builtin_amdgcn_mfma_f32_16x16x32_bf16(aq1, b1, a, 0, 0, 0);
#pragma unroll
      for (int r = 0; r < 4; ++r) {
        int row = wrow + quad * 4 + r;
        sc[ct][r] = a[r] * 0.125f + S2c[row * 66 + ct * 16 + ln15];
      }
    }
#pragma unroll
    for (int r = 0; r < 4; ++r) {
      float tm = fmaxf(fmaxf(sc[0][r], sc[1][r]), fmaxf(sc[2][r], sc[3][r]));
      tm = fmaxf(tm, __shfl_xor(tm, 1));
      tm = fmaxf(tm, __shfl_xor(tm, 2));
      tm = fmaxf(tm, __shfl_xor(tm, 4));
      tm = fmaxf(tm, __shfl_xor(tm, 8));
      float mn = fmaxf(mrow[r], tm);
      float alpha = __expf(mrow[r] - mn);
      mrow[r] = mn;
      float rs = 0.f;
#pragma unroll
      for (int ct = 0; ct < 4; ++ct) {
        float p = __expf(sc[ct][r] - mn);
        sc[ct][r] = p;
        rs += p;
      }
      rs += __shfl_xor(rs, 1); rs += __shfl_xor(rs, 2);
      rs += __shfl_xor(rs, 4); rs += __shfl_xor(rs, 8);
      lrow[r] = lrow[r] * alpha + rs;
#pragma unroll
      for (int ct = 0; ct < 4; ++ct) o[ct][r] *= alpha;
    }
#pragma unroll
    for (int ct = 0; ct < 4; ++ct)
#pragma unroll
      for (int r = 0; r < 4; ++r)
        Ps[(wrow + quad * 4 + r) * 72 + ct * 16 + ln15] = __float2bfloat16(sc[ct][r]);

    bhalf8 ap0 = *(bhalf8*)&Ps[(wrow + ln15) * 72 + quad * 8];
    bhalf8 ap1 = *(bhalf8*)&Ps[(wrow + ln15) * 72 + quad * 8 + 32];
#pragma unroll
    for (int ct = 0; ct < 4; ++ct) {
      bhalf8 b0 = *(bhalf8*)&Vs[(ct * 16 + ln15) * 72 + quad * 8];
      bhalf8 b1 = *(bhalf8*)&Vs[(ct * 16 + ln15) * 72 + quad * 8 + 32];
      o[ct] = __builtin_amdgcn_mfma_f32_16x16x32_bf16(ap0, b0, o[ct], 0, 0, 0);
      o[ct] = __builtin_amdgcn_mfma_f32_16x16x32_bf16(ap1, b1, o[ct], 0, 0, 0);
    }
  }

  // epilogue: locally-normalized partial + (m,l)
  bf16* Oz = Opart + (size_t)z * SEQ * DM;
#pragma unroll
  for (int r = 0; r < 4; ++r) {
    float inv = 1.f / lrow[r];
    int row = i0 + wrow + quad * 4 + r;
#pragma unroll
    for (int ct = 0; ct < 4; ++ct)
      Oz[(size_t)row * DM + h * HDM + ct * 16 + ln15] =
          __float2bfloat16(o[ct][r] * inv);
    if (ln15 == 0) {
      float* mlp = ml + (((size_t)z * NH + h) * SEQ + row) * 2;
      mlp[0] = mrow[r];
      mlp[1] = lrow[r];
    }
  }
}

// ---- merge the two key-halves: O = w0*O0n + w1*O1n
__global__ __launch_bounds__(256) void attn_merge(
    const bf16* __restrict__ O0, const bf16* __restrict__ O1,
    const float* __restrict__ ml, bf16* __restrict__ O)
{
  const int i = blockIdx.x;
  const int tid = threadIdx.x;
  __shared__ float w0s[NH], w1s[NH];
  if (tid < NH) {
    const float* p0 = ml + (((size_t)0 * NH + tid) * SEQ + i) * 2;
    const float* p1 = ml + (((size_t)1 * NH + tid) * SEQ + i) * 2;
    float m0 = p0[0], l0 = p0[1], m1 = p1[0], l1 = p1[1];
    float m = fmaxf(m0, m1);
    float a = l0 * __expf(m0 - m), b = l1 * __expf(m1 - m);
    float inv = 1.f / (a + b);
    w0s[tid] = a * inv; w1s[tid] = b * inv;
  }
  __syncthreads();
  const int d = tid * 4;
  const float w0 = w0s[d >> 6], w1 = w1s[d >> 6];
  union { bf16 h[4]; float2 f; } a0, a1, ov;
  a0.f = *(const float2*)&O0[(size_t)i * DM + d];
  a1.f = *(const float2*)&O1[(size_t)i * DM + d];
#pragma unroll
  for (int e = 0; e < 4; ++e)
    ov.h[e] = __float2bfloat16(w0 * __bfloat162float(a0.h[e]) +
                               w1 * __bfloat162float(a1.h[e]));
  *(float2*)&O[(size_t)i * DM + d] = ov.f;
}

extern "C" void kernel_launch(void* const* d_in, const int* in_sizes, int n_in,
                              void* d_out, int out_size, void* d_ws, size_t ws_size,
                              hipStream_t stream) {
  const float* x   = (const float*)d_in[0];
  const float* Wq  = (const float*)d_in[1];
  const float* bq  = (const float*)d_in[2];
  const float* Wk  = (const float*)d_in[3];
  const float* bk  = (const float*)d_in[4];
  const float* Wv  = (const float*)d_in[5];
  const float* bv  = (const float*)d_in[6];
  const float* Wo  = (const float*)d_in[7];
  const float* bo  = (const float*)d_in[8];
  const float* rel = (const float*)d_in[9];
  float* out = (float*)d_out;

  const size_t SD = (size_t)SEQ * DM;      // 2M elems
  bf16* qws = (bf16*)d_ws;                 // [H][S][64]
  bf16* kws = qws + SD;                    // [H][S][64]
  bf16* vws = kws + SD;                    // Vt [D][S]
  bf16* ows = vws + SD;                    // [S][D] merged attn out
  bf16* xbf = ows + SD;                    // [S][D]
  bf16* wt  = xbf + SD;                    // 4 x [n][k] (q,k,v,o)
  bf16* tbf = wt + 4 * (size_t)DM * DM;    // [4096][64]
  bf16* opart = tbf + (size_t)4096 * HDM;  // 2 x [S][D] partials
  float* ml   = (float*)(opart + 2 * SD);  // [2][NH][SEQ][2]

  convert_inputs<<<2304, 256, 0, stream>>>(x, rel, xbf, tbf);
  transpose_w<<<dim3(16, 16, 4), 256, 0, stream>>>(Wq, Wk, Wv, Wo, wt);
  gemm_qkv<<<dim3(8, 16, 3), 256, 0, stream>>>(xbf, wt, bq, bk, bv, qws);
  attn_flash<<<dim3(SEQ / 64, NH, 2), 256, 0, stream>>>(qws, kws, vws, tbf,
                                                        opart, ml);
  attn_merge<<<SEQ, 256, 0, stream>>>(opart, opart + SD, ml, ows);
  gemm_out<<<dim3(8, 16), 256, 0, stream>>>(ows, wt + 3 * (size_t)DM * DM, bo, out);
}